// Round 1
// baseline (4197.876 us; speedup 1.0000x reference)
//
#include <hip/hip_runtime.h>
#include <hip/hip_bf16.h>
#include <math.h>

// ---------------- dtype helpers (runtime fp32-vs-bf16 sniff) ----------------

__device__ __forceinline__ float bf2f(unsigned short u) {
    union { unsigned int i; float f; } x; x.i = ((unsigned int)u) << 16; return x.f;
}
__device__ __forceinline__ unsigned short f2bf(float f) {
    union { float f; unsigned int i; } x; x.f = f;
    unsigned int i = x.i;
    unsigned int r = (i + 0x7FFFu + ((i >> 16) & 1u)) >> 16;
    return (unsigned short)r;
}
__device__ __forceinline__ float ld1(const void* p, long i, bool bf) {
    return bf ? bf2f(((const unsigned short*)p)[i]) : ((const float*)p)[i];
}
__device__ __forceinline__ float4 ld4(const void* p, long i, bool bf) {
    if (bf) {
        ushort4 u = *(const ushort4*)((const unsigned short*)p + i);
        return make_float4(bf2f(u.x), bf2f(u.y), bf2f(u.z), bf2f(u.w));
    }
    return *(const float4*)((const float*)p + i);
}

// Detect whether float tensors are bf16-packed: look at low 16 bits of words of x
// (N(0,1) values). If bf16, bits[14:7] are an exponent near 127 (0x70..0x85
// almost always). If fp32, those are uniform mantissa bits (~8.6% hit rate).
__global__ void k_detect(const unsigned int* __restrict__ x, int* __restrict__ flag) {
    int t = threadIdx.x;
    int hits = 0;
    for (int i = 0; i < 64; i++) {
        unsigned int w = x[t * 64 + i];
        unsigned int e = (w >> 7) & 0xFF;
        hits += (e >= 0x70 && e <= 0x85) ? 1 : 0;
    }
    __shared__ int sh[256];
    sh[t] = hits;
    __syncthreads();
    for (int off = 128; off; off >>= 1) {
        if (t < off) sh[t] += sh[t + off];
        __syncthreads();
    }
    if (t == 0) *flag = (sh[0] > 8192) ? 1 : 0;   // 16384 words total
}

// ---------------- CSR build (counting sort by dst) ----------------

__global__ void k_hist(const int* __restrict__ dst, int E, int* __restrict__ counts) {
    int i = blockIdx.x * blockDim.x + threadIdx.x;
    if (i < E) atomicAdd(&counts[dst[i]], 1);
}

// per-block (1024 elems) exclusive scan; emits block sums
__global__ void k_scan_a(const int* __restrict__ counts, int N,
                         int* __restrict__ ex, int* __restrict__ bsums) {
    __shared__ int s[256];
    int t = threadIdx.x;
    int base = blockIdx.x * 1024;
    int v[4]; int sum = 0;
    #pragma unroll
    for (int j = 0; j < 4; j++) {
        int idx = base + t * 4 + j;
        v[j] = (idx < N) ? counts[idx] : 0;
        sum += v[j];
    }
    s[t] = sum;
    __syncthreads();
    for (int off = 1; off < 256; off <<= 1) {
        int x = (t >= off) ? s[t - off] : 0;
        __syncthreads();
        s[t] += x;
        __syncthreads();
    }
    int run = (t > 0) ? s[t - 1] : 0;
    #pragma unroll
    for (int j = 0; j < 4; j++) {
        int idx = base + t * 4 + j;
        if (idx < N) ex[idx] = run;
        run += v[j];
    }
    if (t == 255) bsums[blockIdx.x] = s[255];
}

__global__ void k_scan_b(int* __restrict__ bsums, int nb) {
    __shared__ int s[256];
    int t = threadIdx.x;
    s[t] = (t < nb) ? bsums[t] : 0;
    __syncthreads();
    for (int off = 1; off < 256; off <<= 1) {
        int x = (t >= off) ? s[t - off] : 0;
        __syncthreads();
        s[t] += x;
        __syncthreads();
    }
    if (t < nb) bsums[t] = (t > 0) ? s[t - 1] : 0;
}

__global__ void k_scan_c(const int* __restrict__ ex, const int* __restrict__ bsums,
                         int N, int E, int* __restrict__ row_ptr) {
    int i = blockIdx.x * blockDim.x + threadIdx.x;
    if (i < N) row_ptr[i] = ex[i] + bsums[i >> 10];
    if (i == 0) row_ptr[N] = E;
}

__global__ void k_scatter(const int* __restrict__ src, const int* __restrict__ dst,
                          const void* __restrict__ ewin, const int* __restrict__ dflag,
                          const int* __restrict__ row_ptr, int* __restrict__ cursor,
                          int E, int* __restrict__ es, float* __restrict__ ew) {
    int i = blockIdx.x * blockDim.x + threadIdx.x;
    if (i >= E) return;
    bool bf = (*dflag != 0);
    int d = dst[i];
    int p = row_ptr[d] + atomicAdd(&cursor[d], 1);
    es[p] = src[i];
    ew[p] = ld1(ewin, i, bf);
}

// ---------------- fp32 tiled GEMM: C = act(A[M,K] @ W[K,N] (+ bias)) ----------------
// 64x64 tile, 256 threads, 4x4 microtile, K-tile 16.

__global__ __launch_bounds__(256) void k_gemm(
    const void* __restrict__ A, const void* __restrict__ W, const void* __restrict__ bias,
    float* __restrict__ C, int M, int K, int N,
    int a_is_input, int act, const int* __restrict__ dflag)
{
    const bool inbf = (*dflag != 0);
    const bool abf = a_is_input && inbf;

    __shared__ float As[16][68];   // [k][m], padded to 68 for aligned float4 rows
    __shared__ float Ws[16][64];   // [k][n]

    const int t = threadIdx.x;
    const int tx = t & 15, ty = t >> 4;
    const int m0 = blockIdx.x * 64, n0 = blockIdx.y * 64;

    float acc[4][4] = {};

    for (int k0 = 0; k0 < K; k0 += 16) {
        // A tile: 64 rows x 16 cols
        {
            int r = t >> 2;            // 0..63
            int c = (t & 3) * 4;       // 0,4,8,12
            int gm = m0 + r;
            float4 v = make_float4(0.f, 0.f, 0.f, 0.f);
            if (gm < M) v = ld4(A, (long)gm * K + k0 + c, abf);
            As[c + 0][r] = v.x; As[c + 1][r] = v.y; As[c + 2][r] = v.z; As[c + 3][r] = v.w;
        }
        // W tile: 16 rows x 64 cols
        {
            int r = t >> 4;            // 0..15
            int c = (t & 15) * 4;      // 0..60
            float4 v = make_float4(0.f, 0.f, 0.f, 0.f);
            if (n0 + c < N) v = ld4(W, (long)(k0 + r) * N + n0 + c, inbf);
            Ws[r][c + 0] = v.x; Ws[r][c + 1] = v.y; Ws[r][c + 2] = v.z; Ws[r][c + 3] = v.w;
        }
        __syncthreads();
        #pragma unroll
        for (int kk = 0; kk < 16; kk++) {
            float4 a = *(const float4*)&As[kk][ty * 4];
            float4 b = *(const float4*)&Ws[kk][tx * 4];
            acc[0][0] += a.x * b.x; acc[0][1] += a.x * b.y; acc[0][2] += a.x * b.z; acc[0][3] += a.x * b.w;
            acc[1][0] += a.y * b.x; acc[1][1] += a.y * b.y; acc[1][2] += a.y * b.z; acc[1][3] += a.y * b.w;
            acc[2][0] += a.z * b.x; acc[2][1] += a.z * b.y; acc[2][2] += a.z * b.z; acc[2][3] += a.z * b.w;
            acc[3][0] += a.w * b.x; acc[3][1] += a.w * b.y; acc[3][2] += a.w * b.z; acc[3][3] += a.w * b.w;
        }
        __syncthreads();
    }

    const bool has_bias = (bias != nullptr);
    #pragma unroll
    for (int i = 0; i < 4; i++) {
        int gm = m0 + ty * 4 + i;
        if (gm >= M) continue;
        int gn = n0 + tx * 4;
        if (gn >= N) continue;                 // N % 4 == 0 always -> whole quad in/out
        float4 v = make_float4(acc[i][0], acc[i][1], acc[i][2], acc[i][3]);
        if (has_bias) {
            float4 b = ld4(bias, gn, inbf);
            v.x += b.x; v.y += b.y; v.z += b.z; v.w += b.w;
        }
        if (act) {
            v.x = fmaxf(v.x, 0.f); v.y = fmaxf(v.y, 0.f);
            v.z = fmaxf(v.z, 0.f); v.w = fmaxf(v.w, 0.f);
        }
        *(float4*)&C[(long)gm * N + gn] = v;
    }
}

// ---------------- SPMM: out[d] = act(sum_e w[e]*sup[src[e]] + bias), F=256 ----------------
// one wave per dst node, lane l owns features [4l, 4l+4)

__global__ __launch_bounds__(256) void k_spmm(
    const float* __restrict__ sup, const int* __restrict__ es, const float* __restrict__ ew,
    const int* __restrict__ row_ptr, const void* __restrict__ bias,
    float* __restrict__ out, int Nn, int act, const int* __restrict__ dflag)
{
    const int wave = threadIdx.x >> 6;
    const int lane = threadIdx.x & 63;
    const int node = blockIdx.x * 4 + wave;
    if (node >= Nn) return;
    const bool bf = (*dflag != 0);

    const int e0 = row_ptr[node], e1 = row_ptr[node + 1];
    float4 acc = make_float4(0.f, 0.f, 0.f, 0.f);
    for (int e = e0; e < e1; e++) {
        int s = es[e];
        float w = ew[e];
        float4 v = *(const float4*)&sup[(long)s * 256 + lane * 4];
        acc.x += w * v.x; acc.y += w * v.y; acc.z += w * v.z; acc.w += w * v.w;
    }
    float4 b = ld4(bias, lane * 4, bf);
    acc.x += b.x; acc.y += b.y; acc.z += b.z; acc.w += b.w;
    if (act) {
        acc.x = fmaxf(acc.x, 0.f); acc.y = fmaxf(acc.y, 0.f);
        acc.z = fmaxf(acc.z, 0.f); acc.w = fmaxf(acc.w, 0.f);
    }
    *(float4*)&out[(long)node * 256 + lane * 4] = acc;
}

// ---------------- softmax over NC classes, one wave per row ----------------

__global__ __launch_bounds__(256) void k_softmax(
    const float* __restrict__ logits, void* __restrict__ out, int M, int NC,
    const int* __restrict__ dflag)
{
    const int wave = threadIdx.x >> 6;
    const int lane = threadIdx.x & 63;
    const int row = blockIdx.x * 4 + wave;
    if (row >= M) return;
    const bool bf = (*dflag != 0);

    float v = (lane < NC) ? logits[(long)row * NC + lane] : -INFINITY;
    float m = v;
    #pragma unroll
    for (int off = 32; off; off >>= 1) m = fmaxf(m, __shfl_xor(m, off, 64));
    float p = (lane < NC) ? expf(v - m) : 0.f;
    float s = p;
    #pragma unroll
    for (int off = 32; off; off >>= 1) s += __shfl_xor(s, off, 64);
    if (lane < NC) {
        float r = p / s;
        if (bf) ((unsigned short*)out)[(long)row * NC + lane] = f2bf(r);
        else    ((float*)out)[(long)row * NC + lane] = r;
    }
}

// ---------------- orchestration ----------------

extern "C" void kernel_launch(void* const* d_in, const int* in_sizes, int n_in,
                              void* d_out, int out_size, void* d_ws, size_t ws_size,
                              hipStream_t stream) {
    const void* x    = d_in[0];
    const int*  esrc = (const int*)d_in[1];
    const int*  edst = (const int*)d_in[2];
    const void* ewin = d_in[3];
    const void* w1 = d_in[4],  *b1 = d_in[5];
    const void* w2 = d_in[6],  *b2 = d_in[7];
    const void* wc1 = d_in[8], *bc1 = d_in[9];
    const void* wc2 = d_in[10], *bc2 = d_in[11];
    const void* wc3 = d_in[12], *bc3 = d_in[13];
    const void* wc4 = d_in[14], *bc4 = d_in[15];

    const int HID  = in_sizes[5];                 // 256
    const int IND  = in_sizes[4] / HID;           // 512
    const int HID2 = in_sizes[9];                 // 512
    const int NC   = in_sizes[15];                // 40
    const int M    = in_sizes[0] / IND;           // 100000
    const int E    = in_sizes[1];                 // 3200000

    char* ws = (char*)d_ws;
    int* dflag = (int*)ws;                                        // 256 B slot
    float* bufA = (float*)(ws + 256);                             // M*HID fp32 = 102.4 MB
    float* bufB = (float*)(ws + 256 + 102400000L);                // 102.4 MB
    char*  wsC  = ws + 256 + 204800000L;                          // 204.8 MB (h3/h5)
    char*  wsD  = wsC + 204800000L;                               // 204.8 MB (h4)
    float* bufC = (float*)wsC;
    float* bufD = (float*)wsD;

    // CSR arrays live inside bufC's region (dead before the MLP starts)
    int* counts  = (int*)wsC;
    int* row_ptr = counts + 100352;
    int* cursor  = row_ptr + 100352;
    int* bsums   = cursor + 100352;
    int* ex      = bsums + 1024;
    int* es      = ex + 100352;
    float* ewS   = (float*)(es + E);

    float* logits = bufA;   // reuse after support2 is dead (16 MB < 102.4 MB)

    // 0. dtype sniff
    k_detect<<<1, 256, 0, stream>>>((const unsigned int*)x, dflag);

    // 1. CSR build
    hipMemsetAsync(counts, 0, 100352 * sizeof(int), stream);
    hipMemsetAsync(cursor, 0, 100352 * sizeof(int), stream);
    k_hist<<<(E + 255) / 256, 256, 0, stream>>>(edst, E, counts);
    int nb = (M + 1023) / 1024;                                   // 98
    k_scan_a<<<nb, 256, 0, stream>>>(counts, M, ex, bsums);
    k_scan_b<<<1, 256, 0, stream>>>(bsums, nb);
    k_scan_c<<<(M + 255) / 256, 256, 0, stream>>>(ex, bsums, M, E, row_ptr);
    k_scatter<<<(E + 255) / 256, 256, 0, stream>>>(esrc, edst, ewin, dflag, row_ptr, cursor, E, es, ewS);

    const int gm64 = (M + 63) / 64;   // 1563
    dim3 blk(256);

    // 2. support1 = x @ w1                      [M,512]@[512,256] -> bufA
    k_gemm<<<dim3(gm64, HID / 64), blk, 0, stream>>>(x, w1, nullptr, bufA, M, IND, HID, 1, 0, dflag);
    // 3. h1 = relu(spmm(support1) + b1)        -> bufB
    k_spmm<<<(M + 3) / 4, blk, 0, stream>>>(bufA, es, ewS, row_ptr, b1, bufB, M, 1, dflag);
    // 4. support2 = h1 @ w2                    -> bufA
    k_gemm<<<dim3(gm64, HID / 64), blk, 0, stream>>>(bufB, w2, nullptr, bufA, M, HID, HID, 0, 0, dflag);
    // 5. h2 = spmm(support2) + b2              -> bufB
    k_spmm<<<(M + 3) / 4, blk, 0, stream>>>(bufA, es, ewS, row_ptr, b2, bufB, M, 0, dflag);
    // 6. h3 = relu(h2 @ wc1 + bc1)             [M,256]@[256,512] -> bufC  (CSR now dead)
    k_gemm<<<dim3(gm64, HID2 / 64), blk, 0, stream>>>(bufB, wc1, bc1, bufC, M, HID, HID2, 0, 1, dflag);
    // 7. h4 = relu(h3 @ wc2 + bc2)             -> bufD
    k_gemm<<<dim3(gm64, HID2 / 64), blk, 0, stream>>>(bufC, wc2, bc2, bufD, M, HID2, HID2, 0, 1, dflag);
    // 8. h5 = relu(h4 @ wc3 + bc3)             -> bufC
    k_gemm<<<dim3(gm64, HID2 / 64), blk, 0, stream>>>(bufD, wc3, bc3, bufC, M, HID2, HID2, 0, 1, dflag);
    // 9. logits = h5 @ wc4 + bc4               [M,512]@[512,40] -> bufA
    k_gemm<<<dim3(gm64, 1), blk, 0, stream>>>(bufC, wc4, bc4, logits, M, HID2, NC, 0, 0, dflag);
    // 10. softmax -> d_out
    k_softmax<<<(M + 3) / 4, blk, 0, stream>>>(logits, d_out, M, NC, dflag);
}